// Round 13
// baseline (183.146 us; speedup 1.0000x reference)
//
#include <hip/hip_runtime.h>
#include <math.h>

// NoisyTopkRouter: x[T,2048] @ {Wg,Wn}[8,2048]^T -> logits[T,8] each,
// noisy = noise * softplus(noisy_pre) + gate; top-2 -> softmax -> scatter.
// T = 32768, D = 2048, E = 8, k = 2.
//
// R13 = R7's syncthreads main loop (proven 62.2 us; CH=64, KSL=2, 4
// blocks/CU, global_load_lds staging with XOR-pre-swizzled source,
// wave-uniform WT s_loads, acc[16]/lane) + fused epilogue via the split-K
// flag protocol (threadfence + atomicAdd; second-arriving K-slice block
// runs the 64-token epilogue on L2-hot partials).
// Evidence: R10/R11 (counted-vmcnt + fused epilogue) broke codegen 4x;
// R6 proved syncthreads + fused epilogue is safe. This is the untested
// safe cell. Kills the finalize launch + cold 4 MB re-read (~6-8 us).

#define RD 2048
#define RE 8
#define NE16 16               // stacked experts: 0..7 = gate, 8..15 = noise
#define TOKB 64               // tokens per block (lane = token)
#define CH 64                 // d's per chunk (16 KB per chunk)
#define KSL 2                 // K-slices (blocks per token tile)
#define KLEN (RD / KSL)       // 1024 d's per block
#define NCH (KLEN / CH)       // 16 chunks
#define NW 4                  // waves per block

// ---- kernel 1: WT[d][e] = (e<8 ? Wg[e][d] : Wn[e-8][d]) ----
__global__ __launch_bounds__(256) void transpose_w_kernel(
    const float* __restrict__ Wg, const float* __restrict__ Wn,
    float* __restrict__ WT)
{
    const int idx = blockIdx.x * 256 + threadIdx.x;   // 0 .. 2048*16-1
    const int d = idx >> 4;
    const int e = idx & 15;
    WT[idx] = (e < 8) ? Wg[e * RD + d] : Wn[(e - 8) * RD + d];
}

#define AS1 __attribute__((address_space(1)))
#define AS3 __attribute__((address_space(3)))

__device__ __forceinline__ void gload_lds16(const float* g, float* l) {
    // HBM -> LDS DMA, 16 B per lane; LDS dest = wave-uniform base + lane*16.
    __builtin_amdgcn_global_load_lds((const AS1 unsigned int*)g,
                                     (AS3 unsigned int*)l, 16, 0, 0);
}

// ---- kernel 2: main GEMV (R7 loop) + fused epilogue ----
__global__ __launch_bounds__(256) void router_main_kernel(
    const float* __restrict__ x,
    const float* __restrict__ WT,     // [2048][16]
    const float* __restrict__ bg,
    const float* __restrict__ bn,
    const float* __restrict__ noise,
    float* __restrict__ pws,          // [KSL][T][16] partial sums (d_ws)
    int* __restrict__ flags,          // [T/TOKB], zeroed each call
    float* __restrict__ out_router,
    float* __restrict__ out_experts,
    int T)
{
    __shared__ float xb[2][TOKB * CH];   // 2 x 16 KB double buffer

    const int tid = threadIdx.x;
    const int w = tid >> 6;              // wave 0..3 -> 16-d sub-range
    const int l = tid & 63;              // lane = token within tile
    const int NTB = T / TOKB;
    const int bt = blockIdx.x % NTB;     // token tile
    const int kslice = blockIdx.x / NTB; // K-slice
    const int tokBase = bt * TOKB;
    const int kbase = kslice * KLEN;

    float acc[NE16];
#pragma unroll
    for (int e = 0; e < NE16; ++e) acc[e] = 0.f;

    // staging (R7 geometry): per chunk, wave w issues s=0..3; inst (w,s)
    // fills rows t0=(w*4+s)*4 .. +3 (64-float rows). lane -> row
    // t=t0+(l>>4), phys 16B-seg p=l&15; source seg is XOR-pre-swizzled
    // (p ^ (t&7)) so the consume read LDS[l][q ^ (l&7)] = x[l][q] while
    // the LDS dest stays linear (global_load_lds requirement).
    {
#pragma unroll
        for (int s = 0; s < 4; ++s) {
            const int t = (w * 4 + s) * 4 + (l >> 4);
            const int p = l & 15;
            const float* gsrc = x + (size_t)(tokBase + t) * RD + kbase
                                + ((p ^ (t & 7)) << 2);
            gload_lds16(gsrc, &xb[0][(w * 4 + s) * 256]);
        }
    }
    __syncthreads();   // drains vmcnt -> chunk 0 resident

#pragma unroll 1
    for (int c = 0; c < NCH; ++c) {
        const int buf = c & 1;

        if (c + 1 < NCH) {
#pragma unroll
            for (int s = 0; s < 4; ++s) {
                const int t = (w * 4 + s) * 4 + (l >> 4);
                const int p = l & 15;
                const float* gsrc = x + (size_t)(tokBase + t) * RD + kbase
                                    + (c + 1) * CH + ((p ^ (t & 7)) << 2);
                gload_lds16(gsrc, &xb[buf ^ 1][(w * 4 + s) * 256]);
            }
        }

        // consume: wave w covers logical segs q=w*4..w*4+3 (d=c*64+q*4+ii).
        // WT base is wave-uniform -> scalar loads.
        const int wbase = __builtin_amdgcn_readfirstlane(
            (kbase + c * CH + w * 16) * NE16);
        const float* __restrict__ wt = WT + wbase;
#pragma unroll
        for (int r = 0; r < 4; ++r) {
            const int phys = (w * 4 + r) ^ (l & 7);
            const float4 xq = *reinterpret_cast<const float4*>(
                &xb[buf][l * CH + (phys << 2)]);
            const float xs[4] = {xq.x, xq.y, xq.z, xq.w};
#pragma unroll
            for (int ii = 0; ii < 4; ++ii) {
                const float* wrow = wt + (r * 4 + ii) * NE16;
#pragma unroll
                for (int e = 0; e < NE16; ++e)
                    acc[e] = fmaf(xs[ii], wrow[e], acc[e]);
            }
        }

        __syncthreads();   // next chunk landed; this chunk's readers done
    }

    // ---- cross-wave reduction via LDS overlay (xb flat = 8192 floats) ----
    float* red = &xb[0][0];
    {
        const int roff = (w * TOKB + l) * NE16;    // max 4095*.. < 4096*16
        *reinterpret_cast<float4*>(&red[roff + 0])  = make_float4(acc[0], acc[1], acc[2], acc[3]);
        *reinterpret_cast<float4*>(&red[roff + 4])  = make_float4(acc[4], acc[5], acc[6], acc[7]);
        *reinterpret_cast<float4*>(&red[roff + 8])  = make_float4(acc[8], acc[9], acc[10], acc[11]);
        *reinterpret_cast<float4*>(&red[roff + 12]) = make_float4(acc[12], acc[13], acc[14], acc[15]);
    }
    __syncthreads();

    // 256 threads: (token, quad) -> sum 4 wave partials, store one float4
    {
        const int tok = tid >> 2;
        const int q4 = tid & 3;
        float4 s = make_float4(0.f, 0.f, 0.f, 0.f);
#pragma unroll
        for (int wv = 0; wv < NW; ++wv) {
            const float4 a = *reinterpret_cast<const float4*>(
                &red[(wv * TOKB + tok) * NE16 + q4 * 4]);
            s.x += a.x; s.y += a.y; s.z += a.z; s.w += a.w;
        }
        float* dst = pws + ((size_t)kslice * T + tokBase + tok) * NE16 + q4 * 4;
        *reinterpret_cast<float4*>(dst) = s;
    }

    // ---- fused finalize: second K-slice block to arrive runs epilogue ----
    __threadfence();                 // release: my partials visible
    __syncthreads();
    int* amF = (int*)&red[4096];     // overlay, past the reduction area
    if (tid == 0) *amF = atomicAdd(flags + bt, 1);
    __syncthreads();
    if (*amF != 1) return;           // first arriver exits
    __threadfence();                 // acquire: other block's partials visible

    if (tid < TOKB) {
        const int tok = tokBase + tid;
        const float* pp0 = pws + (size_t)tok * NE16;
        const float* pp1 = pws + ((size_t)T + tok) * NE16;

        float g[RE], nn[RE];
#pragma unroll
        for (int e = 0; e < RE; ++e) {
            g[e]  = pp0[e] + pp1[e] + bg[e];
            nn[e] = pp0[8 + e] + pp1[8 + e] + bn[e];
        }

        const float4* nzp = reinterpret_cast<const float4*>(noise + (size_t)tok * RE);
        const float4 nz0 = nzp[0];
        const float4 nz1 = nzp[1];
        const float nzv[RE] = {nz0.x, nz0.y, nz0.z, nz0.w,
                               nz1.x, nz1.y, nz1.z, nz1.w};

        float v[RE];
#pragma unroll
        for (int e = 0; e < RE; ++e) {
            const float p = nn[e];
            // stable softplus: max(p,0) + log1p(exp(-|p|))
            const float sp = fmaxf(p, 0.f) + log1pf(expf(-fabsf(p)));
            v[e] = fmaf(nzv[e], sp, g[e]);
        }

        // top-2 of 8; strict '>' keeps the lowest index on ties, matching
        // jax.lax.top_k / torch.topk ordering.
        int i1 = 0; float m1 = v[0];
#pragma unroll
        for (int e = 1; e < RE; ++e)
            if (v[e] > m1) { m1 = v[e]; i1 = e; }
        int i2 = -1; float m2 = -INFINITY;
#pragma unroll
        for (int e = 0; e < RE; ++e)
            if (e != i1 && v[e] > m2) { m2 = v[e]; i2 = e; }

        const float e2 = expf(m2 - m1);
        const float inv = 1.f / (1.f + e2);
        const float p1s = inv;
        const float p2s = e2 * inv;

        float r[RE];
#pragma unroll
        for (int e = 0; e < RE; ++e)
            r[e] = (e == i1) ? p1s : ((e == i2) ? p2s : 0.f);

        float4* orow = reinterpret_cast<float4*>(out_router + (size_t)tok * RE);
        orow[0] = make_float4(r[0], r[1], r[2], r[3]);
        orow[1] = make_float4(r[4], r[5], r[6], r[7]);

        float2* erow = reinterpret_cast<float2*>(out_experts + (size_t)tok * 2);
        *erow = make_float2((float)i1, (float)i2);
    }
}

extern "C" void kernel_launch(void* const* d_in, const int* in_sizes, int n_in,
                              void* d_out, int out_size, void* d_ws, size_t ws_size,
                              hipStream_t stream) {
    const float* x   = (const float*)d_in[0];
    const float* Wg  = (const float*)d_in[1];
    const float* bg  = (const float*)d_in[2];
    const float* Wn  = (const float*)d_in[3];
    const float* bn  = (const float*)d_in[4];
    const float* nz  = (const float*)d_in[5];
    const int T = in_sizes[0] / RD;              // 32768
    const int NTB = T / TOKB;                    // 512

    float* WT   = (float*)d_ws;                  // 128 KB
    float* pws  = WT + (size_t)RD * NE16;        // KSL*T*16 floats = 4 MB
    int* flags  = (int*)(pws + (size_t)KSL * T * NE16);  // 2 KB

    float* out_router  = (float*)d_out;                // T*8 floats
    float* out_experts = out_router + (size_t)T * RE;  // T*2 floats (as f32)

    hipMemsetAsync(flags, 0, NTB * sizeof(int), stream);

    hipLaunchKernelGGL(transpose_w_kernel, dim3((RD * NE16) / 256), dim3(256),
                       0, stream, Wg, Wn, WT);

    hipLaunchKernelGGL(router_main_kernel, dim3(NTB * KSL), dim3(256), 0,
                       stream, x, WT, bg, bn, nz, pws, flags,
                       out_router, out_experts, T);
}

// Round 14
// 60.944 us; speedup vs baseline: 3.0052x; 3.0052x over previous
//
#include <hip/hip_runtime.h>
#include <math.h>

// NoisyTopkRouter: x[T,2048] @ {Wg,Wn}[8,2048]^T -> logits[T,8] each,
// noisy = noise * softplus(noisy_pre) + gate; top-2 -> softmax -> scatter.
// T = 32768, D = 2048, E = 8, k = 2.
//
// R14 = R9 (proven 60.8 us) with ring DEPTH 4 -> 5: three chunks of DMA in
// flight across every barrier (WAITVM(6)) instead of two. LDS 40960 B ->
// still exactly 4 blocks/CU. Everything else verbatim R9.
// Hard-won rules honored: (1) epilogue/atomic protocol NEVER in the DMA
// kernel (R10/R11/R13 all ~4x); (2) stage BEFORE the counted wait (R10);
// (3) keep W on the wave-uniform WT scalar path (R12 showed LDS-W neutral).

#define RD 2048
#define RE 8
#define NE16 16               // stacked experts: 0..7 = gate, 8..15 = noise
#define TOKB 64               // tokens per block (lane = token)
#define CH 32                 // d's per chunk (8 KB per chunk)
#define KSL 2                 // K-slices (blocks per token tile)
#define KLEN (RD / KSL)       // 1024 d's per block
#define NCH (KLEN / CH)       // 32 chunks
#define NW 4                  // waves per block
#define DEPTH 5               // LDS ring depth (40960 B -> 4 blocks/CU)
#define CHF (TOKB * CH)       // floats per ring slot (2048)

#define AS1 __attribute__((address_space(1)))
#define AS3 __attribute__((address_space(3)))

#define WAITVM(N) asm volatile("s_waitcnt vmcnt(" #N ")" ::: "memory")

__device__ __forceinline__ void gload_lds16(const float* g, float* l) {
    // HBM -> LDS DMA, 16 B per lane; LDS dest is wave-uniform base + lane*16.
    __builtin_amdgcn_global_load_lds((const AS1 unsigned int*)g,
                                     (AS3 unsigned int*)l, 16, 0, 0);
}

// ---- kernel 1: WT[d][e] = (e<8 ? Wg[e][d] : Wn[e-8][d]) ----
__global__ __launch_bounds__(256) void transpose_w_kernel(
    const float* __restrict__ Wg, const float* __restrict__ Wn,
    float* __restrict__ WT)
{
    const int idx = blockIdx.x * 256 + threadIdx.x;   // 0 .. 2048*16-1
    const int d = idx >> 4;
    const int e = idx & 15;
    WT[idx] = (e < 8) ? Wg[e * RD + d] : Wn[(e - 8) * RD + d];
}

// ---- kernel 2: main GEMV, one K-slice per block, partials to d_ws ----
__global__ __launch_bounds__(256) void router_main_kernel(
    const float* __restrict__ x,
    const float* __restrict__ WT,     // [2048][16]
    float* __restrict__ pws,          // [KSL][T][16] partial sums
    int T)
{
    __shared__ float xb[DEPTH][CHF];   // 5 x 8 KB ring

    const int tid = threadIdx.x;
    const int w = tid >> 6;              // wave 0..3 -> 8-d sub-range of chunk
    const int l = tid & 63;              // lane = token within tile
    const int NTB = T / TOKB;
    const int bt = blockIdx.x % NTB;     // token tile
    const int kslice = blockIdx.x / NTB; // K-slice
    const int tokBase = bt * TOKB;
    const int kbase = kslice * KLEN;

    float acc[NE16];
#pragma unroll
    for (int e = 0; e < NE16; ++e) acc[e] = 0.f;

    // Staging geometry (per chunk): 8 x 1 KB DMA insts; inst i = w*2+s
    // covers token rows i*8 .. i*8+7 (32-float rows, 8 16B-segs each).
    // lane -> row t = i*8 + (l>>3)  (so t&7 == l>>3), phys seg p = l&7;
    // the GLOBAL source seg is XOR-pre-swizzled (p ^ (t&7)) so the consume
    // side's swizzled read is bank-friendly while the LDS dest stays linear.
    const size_t laneoff = (size_t)(l >> 3) * RD + ((((l & 7) ^ (l >> 3))) << 2);
    const float* p0 = x + (size_t)(tokBase + (w * 2 + 0) * 8) * RD + kbase + laneoff;
    const float* p1 = x + (size_t)(tokBase + (w * 2 + 1) * 8) * RD + kbase + laneoff;
    float* d0base = &xb[0][(w * 2 + 0) * 256];
    float* d1base = &xb[0][(w * 2 + 1) * 256];

    // prologue: stage chunks 0,1,2 (6 insts outstanding per wave)
    gload_lds16(p0 + 0 * CH, d0base + 0 * CHF);
    gload_lds16(p1 + 0 * CH, d1base + 0 * CHF);
    gload_lds16(p0 + 1 * CH, d0base + 1 * CHF);
    gload_lds16(p1 + 1 * CH, d1base + 1 * CHF);
    gload_lds16(p0 + 2 * CH, d0base + 2 * CHF);
    gload_lds16(p1 + 2 * CH, d1base + 2 * CHF);

    int cb = 0;            // ring slot holding chunk c
    int sb = 3;            // ring slot for stage of chunk c+3

#pragma unroll 1
    for (int c = 0; c < NCH; ++c) {
        // stage chunk c+3 FIRST (R9 order), then counted wait: the wait's
        // "all but newest 6" set ends exactly at chunk c's 2 DMA insts.
        if (c + 3 < NCH) {
            gload_lds16(p0 + (c + 3) * CH, d0base + sb * CHF);
            gload_lds16(p1 + (c + 3) * CH, d1base + sb * CHF);
            WAITVM(6);               // chunk c retired; c+1,c+2,c+3 in flight
        } else if (c + 3 == NCH) {
            WAITVM(4);               // chunk c retired; c+1,c+2 in flight
        } else if (c + 2 == NCH) {
            WAITVM(2);               // chunk c retired; c+1 in flight
        } else {
            WAITVM(0);               // last chunk
        }
        __builtin_amdgcn_s_barrier();       // all waves' chunk-c DMA landed
        __builtin_amdgcn_sched_barrier(0);  // no hoisting across

        // consume chunk c: wave w covers logical segs q = w*2, w*2+1
        // (d = kbase + c*32 + q*4 + ii). WT base wave-uniform -> s_load;
        // contiguous 512 B per chunk per wave -> scalar-cache friendly.
        const int wbase = __builtin_amdgcn_readfirstlane(
            (kbase + c * CH + w * 8) * NE16);
        const float* __restrict__ wt = WT + wbase;
#pragma unroll
        for (int r = 0; r < 2; ++r) {
            const int q = w * 2 + r;
            const float4 xq = *reinterpret_cast<const float4*>(
                &xb[cb][l * CH + ((q ^ (l & 7)) << 2)]);
            const float xs[4] = {xq.x, xq.y, xq.z, xq.w};
#pragma unroll
            for (int ii = 0; ii < 4; ++ii) {
                const float* wrow = wt + (r * 4 + ii) * NE16;
#pragma unroll
                for (int e = 0; e < NE16; ++e)
                    acc[e] = fmaf(xs[ii], wrow[e], acc[e]);
            }
        }
        // hazard: stage(c+3) overwrote the slot last holding chunk c-2;
        // all waves' reads of c-2 finished before barrier(c-1), which
        // precedes this iteration's stage. One full barrier of margin.

        if (++cb == DEPTH) cb = 0;
        if (++sb == DEPTH) sb = 0;
    }

    __syncthreads();   // everything retired; safe to overlay xb

    // ---- cross-wave reduction overlay (needs 4096 floats of xb) ----
    float* red = &xb[0][0];
    {
        const int roff = (w * TOKB + l) * NE16;
        *reinterpret_cast<float4*>(&red[roff + 0])  = make_float4(acc[0], acc[1], acc[2], acc[3]);
        *reinterpret_cast<float4*>(&red[roff + 4])  = make_float4(acc[4], acc[5], acc[6], acc[7]);
        *reinterpret_cast<float4*>(&red[roff + 8])  = make_float4(acc[8], acc[9], acc[10], acc[11]);
        *reinterpret_cast<float4*>(&red[roff + 12]) = make_float4(acc[12], acc[13], acc[14], acc[15]);
    }
    __syncthreads();

    // 256 threads: (token, quad) -> sum 4 wave partials, one float4 out
    {
        const int tok = tid >> 2;
        const int q4 = tid & 3;
        float4 s = make_float4(0.f, 0.f, 0.f, 0.f);
#pragma unroll
        for (int wv = 0; wv < NW; ++wv) {
            const float4 a = *reinterpret_cast<const float4*>(
                &red[(wv * TOKB + tok) * NE16 + q4 * 4]);
            s.x += a.x; s.y += a.y; s.z += a.z; s.w += a.w;
        }
        float* dst = pws + ((size_t)kslice * T + tokBase + tok) * NE16 + q4 * 4;
        *reinterpret_cast<float4*>(dst) = s;
    }
}

// ---- kernel 3: combine K-slices + epilogue ----
__global__ __launch_bounds__(256) void router_finalize_kernel(
    const float* __restrict__ pws,
    const float* __restrict__ bg,
    const float* __restrict__ bn,
    const float* __restrict__ noise,
    float* __restrict__ out_router,
    float* __restrict__ out_experts,
    int T)
{
    const int tok = blockIdx.x * 256 + threadIdx.x;

    const float* pp0 = pws + (size_t)tok * NE16;
    const float* pp1 = pws + ((size_t)T + tok) * NE16;

    float g[RE], nn[RE];
#pragma unroll
    for (int e = 0; e < RE; ++e) {
        g[e]  = pp0[e] + pp1[e] + bg[e];
        nn[e] = pp0[8 + e] + pp1[8 + e] + bn[e];
    }

    const float4* nzp = reinterpret_cast<const float4*>(noise + (size_t)tok * RE);
    const float4 nz0 = nzp[0];
    const float4 nz1 = nzp[1];
    const float nzv[RE] = {nz0.x, nz0.y, nz0.z, nz0.w,
                           nz1.x, nz1.y, nz1.z, nz1.w};

    float v[RE];
#pragma unroll
    for (int e = 0; e < RE; ++e) {
        const float p = nn[e];
        // stable softplus: max(p,0) + log1p(exp(-|p|))
        const float sp = fmaxf(p, 0.f) + log1pf(expf(-fabsf(p)));
        v[e] = fmaf(nzv[e], sp, g[e]);
    }

    // top-2 of 8; strict '>' keeps the lowest index on ties, matching
    // jax.lax.top_k / torch.topk ordering.
    int i1 = 0; float m1 = v[0];
#pragma unroll
    for (int e = 1; e < RE; ++e)
        if (v[e] > m1) { m1 = v[e]; i1 = e; }
    int i2 = -1; float m2 = -INFINITY;
#pragma unroll
    for (int e = 0; e < RE; ++e)
        if (e != i1 && v[e] > m2) { m2 = v[e]; i2 = e; }

    const float e2 = expf(m2 - m1);
    const float inv = 1.f / (1.f + e2);
    const float p1s = inv;
    const float p2s = e2 * inv;

    float r[RE];
#pragma unroll
    for (int e = 0; e < RE; ++e)
        r[e] = (e == i1) ? p1s : ((e == i2) ? p2s : 0.f);

    float4* orow = reinterpret_cast<float4*>(out_router + (size_t)tok * RE);
    orow[0] = make_float4(r[0], r[1], r[2], r[3]);
    orow[1] = make_float4(r[4], r[5], r[6], r[7]);

    float2* erow = reinterpret_cast<float2*>(out_experts + (size_t)tok * 2);
    *erow = make_float2((float)i1, (float)i2);
}

extern "C" void kernel_launch(void* const* d_in, const int* in_sizes, int n_in,
                              void* d_out, int out_size, void* d_ws, size_t ws_size,
                              hipStream_t stream) {
    const float* x   = (const float*)d_in[0];
    const float* Wg  = (const float*)d_in[1];
    const float* bg  = (const float*)d_in[2];
    const float* Wn  = (const float*)d_in[3];
    const float* bn  = (const float*)d_in[4];
    const float* nz  = (const float*)d_in[5];
    const int T = in_sizes[0] / RD;              // 32768

    float* WT  = (float*)d_ws;                   // 128 KB
    float* pws = WT + (size_t)RD * NE16;         // KSL*T*16 floats = 4 MB

    float* out_router  = (float*)d_out;                // T*8 floats
    float* out_experts = out_router + (size_t)T * RE;  // T*2 floats (as f32)

    hipLaunchKernelGGL(transpose_w_kernel, dim3((RD * NE16) / 256), dim3(256),
                       0, stream, Wg, Wn, WT);

    const int NTB = T / TOKB;                    // 512
    hipLaunchKernelGGL(router_main_kernel, dim3(NTB * KSL), dim3(256), 0,
                       stream, x, WT, pws, T);

    hipLaunchKernelGGL(router_finalize_kernel, dim3(T / 256), dim3(256), 0,
                       stream, pws, bg, bn, nz, out_router, out_experts, T);
}

// Round 15
// 60.503 us; speedup vs baseline: 3.0270x; 1.0073x over previous
//
#include <hip/hip_runtime.h>
#include <math.h>

// NoisyTopkRouter: x[T,2048] @ {Wg,Wn}[8,2048]^T -> logits[T,8] each,
// noisy = noise * softplus(noisy_pre) + gate; top-2 -> softmax -> scatter.
// T = 32768, D = 2048, E = 8, k = 2.
//
// R15: KSL=1 + 8-wave blocks -> token's full logits are BLOCK-LOCAL, so the
// epilogue fuses without the cursed cross-block flag protocol (R10/R11/R13
// all 4x; block-local epilogue proven safe in R6). Kills finalize kernel,
// pws round-trip, flags, memset. Main loop keeps R9's exact proven cadence:
// stage(c+2) -> WAITVM(4) -> s_barrier -> consume, 2 DMA insts/wave/chunk,
// 128 FMA/wave/chunk, W on the wave-uniform WT scalar path.
// Bonus: CH=64 rows = 16 segs -> 4-bit XOR swizzle -> 4-way LDS conflict
// (was 8-way at CH=32).

#define RD 2048
#define RE 8
#define NE16 16               // stacked experts: 0..7 = gate, 8..15 = noise
#define TOKB 64               // tokens per block (lane = token)
#define CH 64                 // d's per chunk (16 KB per chunk)
#define NCH (RD / CH)         // 32 chunks (full K per block)
#define NWV 8                 // waves per block (512 threads)
#define DEPTH 4               // LDS ring depth (64 KB -> 2 blocks/CU)
#define CHF (TOKB * CH)       // floats per ring slot (4096)

#define AS1 __attribute__((address_space(1)))
#define AS3 __attribute__((address_space(3)))

#define WAITVM(N) asm volatile("s_waitcnt vmcnt(" #N ")" ::: "memory")

__device__ __forceinline__ void gload_lds16(const float* g, float* l) {
    // HBM -> LDS DMA, 16 B per lane; LDS dest is wave-uniform base + lane*16.
    __builtin_amdgcn_global_load_lds((const AS1 unsigned int*)g,
                                     (AS3 unsigned int*)l, 16, 0, 0);
}

// ---- kernel 1: WT[d][e] = (e<8 ? Wg[e][d] : Wn[e-8][d]) ----
__global__ __launch_bounds__(256) void transpose_w_kernel(
    const float* __restrict__ Wg, const float* __restrict__ Wn,
    float* __restrict__ WT)
{
    const int idx = blockIdx.x * 256 + threadIdx.x;   // 0 .. 2048*16-1
    const int d = idx >> 4;
    const int e = idx & 15;
    WT[idx] = (e < 8) ? Wg[e * RD + d] : Wn[(e - 8) * RD + d];
}

// ---- kernel 2: main GEMV, full K per block, inline block-local epilogue ----
__global__ __launch_bounds__(512, 4) void router_main_kernel(
    const float* __restrict__ x,
    const float* __restrict__ WT,     // [2048][16]
    const float* __restrict__ bg,
    const float* __restrict__ bn,
    const float* __restrict__ noise,
    float* __restrict__ out_router,
    float* __restrict__ out_experts,
    int T)
{
    __shared__ float xb[DEPTH][CHF];   // 4 x 16 KB ring; overlaid later

    const int tid = threadIdx.x;
    const int w = tid >> 6;              // wave 0..7 -> 8-d sub-range of chunk
    const int l = tid & 63;              // lane = token within tile
    const int tokBase = blockIdx.x * TOKB;

    float acc[NE16];
#pragma unroll
    for (int e = 0; e < NE16; ++e) acc[e] = 0.f;

    // Staging geometry (per chunk): 16 x 1 KB DMA insts; inst i covers token
    // rows i*4 .. i*4+3 (64-float / 256 B rows, 16 16B-segs each). Wave w
    // issues insts i = 2w, 2w+1. lane -> row t = i*4 + (l>>4), phys seg
    // p = l&15; the GLOBAL source seg is XOR-pre-swizzled (p ^ (t&15)):
    // LDS[t][s] holds x[t][s ^ (t&15)], so the consume read
    // LDS[l][q ^ (l&15)] = x[l][q] spreads 64 lanes over 16 seg-slots
    // (4-way bank conflict) while the LDS dest stays linear.
    const int iA = w * 2 + 0, iB = w * 2 + 1;
    const int tA = iA * 4 + (l >> 4), tB = iB * 4 + (l >> 4);
    const size_t offA = (size_t)(tokBase + tA) * RD + (((l & 15) ^ (tA & 15)) << 2);
    const size_t offB = (size_t)(tokBase + tB) * RD + (((l & 15) ^ (tB & 15)) << 2);
    const float* pA = x + offA;
    const float* pB = x + offB;
    float* dA = &xb[0][iA * 256];
    float* dB = &xb[0][iB * 256];

    // prologue: stage chunks 0 and 1 (4 insts outstanding per wave)
    gload_lds16(pA + 0 * CH, dA + 0 * CHF);
    gload_lds16(pB + 0 * CH, dB + 0 * CHF);
    gload_lds16(pA + 1 * CH, dA + 1 * CHF);
    gload_lds16(pB + 1 * CH, dB + 1 * CHF);

#pragma unroll 1
    for (int c = 0; c < NCH; ++c) {
        const int b = c & (DEPTH - 1);

        // stage chunk c+2 FIRST (R9 order), then counted wait: the wait's
        // "all but newest 4" set ends exactly at chunk c's 2 DMA insts.
        if (c + 2 < NCH) {
            const int nb = (c + 2) & (DEPTH - 1);
            gload_lds16(pA + (c + 2) * CH, dA + nb * CHF);
            gload_lds16(pB + (c + 2) * CH, dB + nb * CHF);
            WAITVM(4);               // chunk c retired; c+1,c+2 in flight
        } else if (c + 2 == NCH) {
            WAITVM(2);               // chunk c retired; c+1 in flight
        } else {
            WAITVM(0);               // last chunk
        }
        __builtin_amdgcn_s_barrier();       // all waves' chunk-c DMA landed
        __builtin_amdgcn_sched_barrier(0);  // no hoisting across

        // consume chunk c: wave w covers logical segs q = 2w, 2w+1
        // (d = c*64 + q*4 + ii). WT base wave-uniform -> s_load;
        // contiguous 512 B per chunk per wave -> scalar-cache friendly.
        const int wbase = __builtin_amdgcn_readfirstlane(
            (c * CH + w * 8) * NE16);
        const float* __restrict__ wt = WT + wbase;
#pragma unroll
        for (int r = 0; r < 2; ++r) {
            const int q = w * 2 + r;
            const float4 xq = *reinterpret_cast<const float4*>(
                &xb[b][l * CH + ((q ^ (l & 15)) << 2)]);
            const float xs[4] = {xq.x, xq.y, xq.z, xq.w};
#pragma unroll
            for (int ii = 0; ii < 4; ++ii) {
                const float* wrow = wt + (r * 4 + ii) * NE16;
#pragma unroll
                for (int e = 0; e < NE16; ++e)
                    acc[e] = fmaf(xs[ii], wrow[e], acc[e]);
            }
        }
        // hazard: stage(c+2) overwrote the slot last holding chunk c-2;
        // all waves' reads of c-2 finished before barrier(c-1). Safe.
    }

    __syncthreads();   // everything retired; safe to overlay xb

    // ---- cross-wave reduction overlay: red[8][64][16] = 8192 floats ----
    float* red = &xb[0][0];
    {
        const int roff = (w * TOKB + l) * NE16;
        *reinterpret_cast<float4*>(&red[roff + 0])  = make_float4(acc[0], acc[1], acc[2], acc[3]);
        *reinterpret_cast<float4*>(&red[roff + 4])  = make_float4(acc[4], acc[5], acc[6], acc[7]);
        *reinterpret_cast<float4*>(&red[roff + 8])  = make_float4(acc[8], acc[9], acc[10], acc[11]);
        *reinterpret_cast<float4*>(&red[roff + 12]) = make_float4(acc[12], acc[13], acc[14], acc[15]);
    }
    __syncthreads();

    // 512 threads: (token, pair) -> sum 8 wave partials of 2 floats each
    float* glog = &red[NWV * TOKB * NE16];      // overlay: [64][16] floats
    {
        const int t = tid >> 3;
        const int pr = (tid & 7) * 2;
        float s0 = 0.f, s1 = 0.f;
#pragma unroll
        for (int wv = 0; wv < NWV; ++wv) {
            s0 += red[(wv * TOKB + t) * NE16 + pr];
            s1 += red[(wv * TOKB + t) * NE16 + pr + 1];
        }
        glog[t * NE16 + pr] = s0;
        glog[t * NE16 + pr + 1] = s1;
    }
    __syncthreads();

    // ---- inline epilogue: 64 threads, one token each (block-local!) ----
    if (tid < TOKB) {
        const int tok = tokBase + tid;
        const float* lg = &glog[tid * NE16];

        const float4* nzp = reinterpret_cast<const float4*>(noise + (size_t)tok * RE);
        const float4 nz0 = nzp[0];
        const float4 nz1 = nzp[1];
        const float nzv[RE] = {nz0.x, nz0.y, nz0.z, nz0.w,
                               nz1.x, nz1.y, nz1.z, nz1.w};

        float v[RE];
#pragma unroll
        for (int e = 0; e < RE; ++e) {
            const float p = lg[8 + e] + bn[e];
            // stable softplus: max(p,0) + log1p(exp(-|p|))
            const float sp = fmaxf(p, 0.f) + log1pf(expf(-fabsf(p)));
            v[e] = fmaf(nzv[e], sp, lg[e] + bg[e]);
        }

        // top-2 of 8; strict '>' keeps the lowest index on ties, matching
        // jax.lax.top_k / torch.topk ordering.
        int i1 = 0; float m1 = v[0];
#pragma unroll
        for (int e = 1; e < RE; ++e)
            if (v[e] > m1) { m1 = v[e]; i1 = e; }
        int i2 = -1; float m2 = -INFINITY;
#pragma unroll
        for (int e = 0; e < RE; ++e)
            if (e != i1 && v[e] > m2) { m2 = v[e]; i2 = e; }

        const float e2 = expf(m2 - m1);
        const float inv = 1.f / (1.f + e2);
        const float p1s = inv;
        const float p2s = e2 * inv;

        float r[RE];
#pragma unroll
        for (int e = 0; e < RE; ++e)
            r[e] = (e == i1) ? p1s : ((e == i2) ? p2s : 0.f);

        float4* orow = reinterpret_cast<float4*>(out_router + (size_t)tok * RE);
        orow[0] = make_float4(r[0], r[1], r[2], r[3]);
        orow[1] = make_float4(r[4], r[5], r[6], r[7]);

        float2* erow = reinterpret_cast<float2*>(out_experts + (size_t)tok * 2);
        *erow = make_float2((float)i1, (float)i2);
    }
}

extern "C" void kernel_launch(void* const* d_in, const int* in_sizes, int n_in,
                              void* d_out, int out_size, void* d_ws, size_t ws_size,
                              hipStream_t stream) {
    const float* x   = (const float*)d_in[0];
    const float* Wg  = (const float*)d_in[1];
    const float* bg  = (const float*)d_in[2];
    const float* Wn  = (const float*)d_in[3];
    const float* bn  = (const float*)d_in[4];
    const float* nz  = (const float*)d_in[5];
    const int T = in_sizes[0] / RD;              // 32768

    float* WT = (float*)d_ws;                    // 128 KB scratch

    float* out_router  = (float*)d_out;                // T*8 floats
    float* out_experts = out_router + (size_t)T * RE;  // T*2 floats (as f32)

    hipLaunchKernelGGL(transpose_w_kernel, dim3((RD * NE16) / 256), dim3(256),
                       0, stream, Wg, Wn, WT);

    const int blocks = T / TOKB;                 // 512
    hipLaunchKernelGGL(router_main_kernel, dim3(blocks), dim3(512), 0,
                       stream, x, WT, bg, bn, nz, out_router, out_experts, T);
}